// Round 5
// baseline (400.913 us; speedup 1.0000x reference)
//
#include <hip/hip_runtime.h>
#include <math.h>

#define IMG 512
#define PLANES 96            // 32 N * 3 C
#define XS_W 54              // valid output columns per wave (64 lanes - 10 halo)
#define NXS 10               // ceil(512/54)
#define YS_H 128             // output rows per wave
#define NYS 4                // 512/128
#define WPB 4                // waves per block
#define NBLK ((PLANES * NXS * NYS) / WPB)   // 960 blocks
#define INV_NPIX (1.0 / 25165824.0)

// ws layout: float4 part[NBLK] (15360 B) — per-block partial sums, plain stores.

static __device__ __forceinline__ float rflf(float x) {
    return __int_as_float(__builtin_amdgcn_readfirstlane(__float_as_int(x)));
}

// DPP wave-wide lane shifts (VALU pipe). wave_shr:1 (0x138): lane i reads lane i-1.
// wave_shl:1 (0x130): lane i reads lane i+1. bound_ctrl: OOB lanes read 0 —
// consumed only by halo lanes that never emit.
static __device__ __forceinline__ float dpp_shr1(float x) {
    return __int_as_float(__builtin_amdgcn_mov_dpp(__float_as_int(x), 0x138, 0xF, 0xF, true));
}
static __device__ __forceinline__ float dpp_shl1(float x) {
    return __int_as_float(__builtin_amdgcn_mov_dpp(__float_as_int(x), 0x130, 0xF, 0xF, true));
}

// One row step, phase P = t % 11. Vertical ring: slot (P+j+1)%11 += g[10-j]*H;
// j==10 overwrites the slot emitted last step (mul, no zeroing). Emit slot (P+1)%11.
// Arithmetic and accumulation order identical to the verified R4 kernel.
template<int P, bool EMIT>
__device__ __forceinline__ void row_step(
    int T, int y0s,
    const float* __restrict__ b1, const float* __restrict__ b2,   // SGPR plane bases
    unsigned colc, bool col_ok,
    float& x1, float& x2, const float (&g)[11],
    float (&A)[5][11], bool out_ok, float& sL, float& sC, float& sS)
{
    const int t = T + P;
    // ---- prefetch row t+1: wave-uniform row branch, clamped col, cndmask zero ----
    const int gy = y0s - 4 + t;                    // uniform (scalar branch)
    float nx1 = 0.f, nx2 = 0.f;
    if ((unsigned)gy < IMG) {
        unsigned idx = (unsigned)(gy * IMG) + colc;
        float r1 = b1[idx];
        float r2 = b2[idx];
        nx1 = col_ok ? r1 : 0.f;
        nx2 = col_ok ? r2 : 0.f;
    }
    // ---- horizontal window: left chain materialized, right chain rolled ----
    float a4 = dpp_shr1(x1), b4 = dpp_shr1(x2);
    float a3 = dpp_shr1(a4), b3 = dpp_shr1(b4);
    float a2 = dpp_shr1(a3), b2r = dpp_shr1(b3);
    float a1 = dpp_shr1(a2), b1r = dpp_shr1(b2r);
    float a0 = dpp_shr1(a1), b0 = dpp_shr1(b1r);
    // j = 0
    float t1 = g[0] * a0, t2 = g[0] * b0;
    float H1 = t1, H2 = t2;
    float H11 = t1 * a0, H22 = t2 * b0, H12 = t1 * b0;
#define HACC(J, AJ, BJ)                                   \
    t1 = g[J] * (AJ); t2 = g[J] * (BJ);                   \
    H1 += t1; H2 += t2;                                   \
    H11 = fmaf(t1, (AJ), H11);                            \
    H22 = fmaf(t2, (BJ), H22);                            \
    H12 = fmaf(t1, (BJ), H12);
    HACC(1, a1, b1r)
    HACC(2, a2, b2r)
    HACC(3, a3, b3)
    HACC(4, a4, b4)
    HACC(5, x1, x2)
    float ar = dpp_shl1(x1), br = dpp_shl1(x2);
    HACC(6, ar, br)
    ar = dpp_shl1(ar); br = dpp_shl1(br);
    HACC(7, ar, br)
    ar = dpp_shl1(ar); br = dpp_shl1(br);
    HACC(8, ar, br)
    ar = dpp_shl1(ar); br = dpp_shl1(br);
    HACC(9, ar, br)
    ar = dpp_shl1(ar); br = dpp_shl1(br);
    HACC(10, ar, br)
#undef HACC
    // ---- vertical ring accumulate (static slot indices, t ≡ P mod 11) ----
    #pragma unroll
    for (int j = 0; j < 11; ++j) {
        const int s = (P + j + 1) % 11;
        float w = g[10 - j];
        if (j == 10) {                             // fresh slot (== P): overwrite
            A[0][s] = w * H1;
            A[1][s] = w * H2;
            A[2][s] = w * H11;
            A[3][s] = w * H22;
            A[4][s] = w * H12;
        } else {
            A[0][s] = fmaf(w, H1,  A[0][s]);
            A[1][s] = fmaf(w, H2,  A[1][s]);
            A[2][s] = fmaf(w, H11, A[2][s]);
            A[3][s] = fmaf(w, H22, A[3][s]);
            A[4][s] = fmaf(w, H12, A[4][s]);
        }
    }
    // ---- emit output row r = t-10 (slot (P+1)%11) ----
    if (EMIT) {
        const int es = (P + 1) % 11;
        float mu1 = A[0][es], mu2 = A[1][es];
        float x11 = A[2][es], x22 = A[3][es], x12 = A[4][es];
        float mu1s = mu1 * mu1, mu2s = mu2 * mu2, mu12 = mu1 * mu2;
        float v1 = x11 - mu1s, v2 = x22 - mu2s, v12 = x12 - mu12;
        float q1 = fabsf(v1), q2 = fabsf(v2);
        float q12 = sqrtf(q1 * q2);                // sqrt(a1)*sqrt(a2)
        const float C1 = 1e-4f, C2 = 9e-4f, C3 = 4.5e-4f;
        float eL = __fdividef(2.f * mu12 + C1, mu1s + mu2s + C1);
        float eC = __fdividef(2.f * q12 + C2, q1 + q2 + C2);
        float eS = __fdividef(v12 + C3, q12 + C3);
        if (out_ok) { sL += eL; sC += eC; sS += eS; }
    }
    x1 = nx1; x2 = nx2;
}

__global__ __launch_bounds__(256, 2) void ssim_main(
    const float* __restrict__ img1, const float* __restrict__ img2,
    const float* __restrict__ win, float4* __restrict__ part)
{
    const int lane = threadIdx.x & 63;
    const int widx = threadIdx.x >> 6;
    const int wid  = blockIdx.x * WPB + widx;
    const int plane = wid / (NXS * NYS);
    const int rem   = wid % (NXS * NYS);
    const int ys = rem / NXS, xs = rem % NXS;
    const int x0 = xs * XS_W;
    const int y0 = ys * YS_H;
    const int col = x0 - 5 + lane;                 // this lane's image column
    const bool col_ok = (unsigned)col < IMG;
    const bool out_ok = (lane >= 5) && (lane <= 58) && col_ok;
    const unsigned colc = (unsigned)(col < 0 ? 0 : (col > IMG - 1 ? IMG - 1 : col));

    // wave-uniform scalars -> SGPRs (compiler can't prove threadIdx>>6 uniform)
    const int y0s = __builtin_amdgcn_readfirstlane(y0);
    const int plane_u = __builtin_amdgcn_readfirstlane(plane);
    const float* b1 = img1 + (size_t)plane_u * (IMG * IMG);
    const float* b2 = img2 + (size_t)plane_u * (IMG * IMG);

    // separable 1-D Gaussian from diagonal of 2-D window: g[i] = sqrt(w2d[i][i])
    float g[11];
    #pragma unroll
    for (int j = 0; j < 11; ++j) g[j] = rflf(sqrtf(win[j * 12]));

    // load row t=0 (gy = y0-5)
    float x1 = 0.f, x2 = 0.f;
    {
        int gy = y0s - 5;
        if ((unsigned)gy < IMG) {
            unsigned idx = (unsigned)(gy * IMG) + colc;
            float r1 = b1[idx], r2 = b2[idx];
            x1 = col_ok ? r1 : 0.f;
            x2 = col_ok ? r2 : 0.f;
        }
    }

    float A[5][11];
    #pragma unroll
    for (int q = 0; q < 5; ++q)
        #pragma unroll
        for (int s = 0; s < 11; ++s) A[q][s] = 0.f;

    float sL = 0.f, sC = 0.f, sS = 0.f;

    // t = 0..10: first 10 steps produce no output (ring warm-up), t=10 emits row 0
    row_step<0,false>(0, y0s, b1, b2, colc, col_ok, x1, x2, g, A, out_ok, sL, sC, sS);
    row_step<1,false>(0, y0s, b1, b2, colc, col_ok, x1, x2, g, A, out_ok, sL, sC, sS);
    row_step<2,false>(0, y0s, b1, b2, colc, col_ok, x1, x2, g, A, out_ok, sL, sC, sS);
    row_step<3,false>(0, y0s, b1, b2, colc, col_ok, x1, x2, g, A, out_ok, sL, sC, sS);
    row_step<4,false>(0, y0s, b1, b2, colc, col_ok, x1, x2, g, A, out_ok, sL, sC, sS);
    row_step<5,false>(0, y0s, b1, b2, colc, col_ok, x1, x2, g, A, out_ok, sL, sC, sS);
    row_step<6,false>(0, y0s, b1, b2, colc, col_ok, x1, x2, g, A, out_ok, sL, sC, sS);
    row_step<7,false>(0, y0s, b1, b2, colc, col_ok, x1, x2, g, A, out_ok, sL, sC, sS);
    row_step<8,false>(0, y0s, b1, b2, colc, col_ok, x1, x2, g, A, out_ok, sL, sC, sS);
    row_step<9,false>(0, y0s, b1, b2, colc, col_ok, x1, x2, g, A, out_ok, sL, sC, sS);
    row_step<10,true>(0, y0s, b1, b2, colc, col_ok, x1, x2, g, A, out_ok, sL, sC, sS);

    #pragma unroll 1
    for (int T = 11; T < 132; T += 11) {           // t = 11..131, all emit
        row_step<0,true>(T, y0s, b1, b2, colc, col_ok, x1, x2, g, A, out_ok, sL, sC, sS);
        row_step<1,true>(T, y0s, b1, b2, colc, col_ok, x1, x2, g, A, out_ok, sL, sC, sS);
        row_step<2,true>(T, y0s, b1, b2, colc, col_ok, x1, x2, g, A, out_ok, sL, sC, sS);
        row_step<3,true>(T, y0s, b1, b2, colc, col_ok, x1, x2, g, A, out_ok, sL, sC, sS);
        row_step<4,true>(T, y0s, b1, b2, colc, col_ok, x1, x2, g, A, out_ok, sL, sC, sS);
        row_step<5,true>(T, y0s, b1, b2, colc, col_ok, x1, x2, g, A, out_ok, sL, sC, sS);
        row_step<6,true>(T, y0s, b1, b2, colc, col_ok, x1, x2, g, A, out_ok, sL, sC, sS);
        row_step<7,true>(T, y0s, b1, b2, colc, col_ok, x1, x2, g, A, out_ok, sL, sC, sS);
        row_step<8,true>(T, y0s, b1, b2, colc, col_ok, x1, x2, g, A, out_ok, sL, sC, sS);
        row_step<9,true>(T, y0s, b1, b2, colc, col_ok, x1, x2, g, A, out_ok, sL, sC, sS);
        row_step<10,true>(T, y0s, b1, b2, colc, col_ok, x1, x2, g, A, out_ok, sL, sC, sS);
    }
    // tail: t = 132..137
    row_step<0,true>(132, y0s, b1, b2, colc, col_ok, x1, x2, g, A, out_ok, sL, sC, sS);
    row_step<1,true>(132, y0s, b1, b2, colc, col_ok, x1, x2, g, A, out_ok, sL, sC, sS);
    row_step<2,true>(132, y0s, b1, b2, colc, col_ok, x1, x2, g, A, out_ok, sL, sC, sS);
    row_step<3,true>(132, y0s, b1, b2, colc, col_ok, x1, x2, g, A, out_ok, sL, sC, sS);
    row_step<4,true>(132, y0s, b1, b2, colc, col_ok, x1, x2, g, A, out_ok, sL, sC, sS);
    row_step<5,true>(132, y0s, b1, b2, colc, col_ok, x1, x2, g, A, out_ok, sL, sC, sS);

    // ---- wave reduction, then block reduction via tiny LDS, one plain store ----
    #pragma unroll
    for (int off = 32; off > 0; off >>= 1) {
        sL += __shfl_down(sL, off, 64);
        sC += __shfl_down(sC, off, 64);
        sS += __shfl_down(sS, off, 64);
    }
    __shared__ float red[WPB][4];
    if (lane == 0) { red[widx][0] = sL; red[widx][1] = sC; red[widx][2] = sS; }
    __syncthreads();
    if (threadIdx.x == 0) {
        float L = 0.f, C = 0.f, S = 0.f;
        #pragma unroll
        for (int w = 0; w < WPB; ++w) { L += red[w][0]; C += red[w][1]; S += red[w][2]; }
        part[blockIdx.x] = make_float4(L, C, S, 0.f);
    }
}

__global__ void ssim_fin(const float4* __restrict__ part, float* __restrict__ out) {
    const int t = threadIdx.x;
    double L = 0.0, C = 0.0, S = 0.0;
    for (int i = t; i < NBLK; i += 256) {
        float4 p = part[i];
        L += (double)p.x; C += (double)p.y; S += (double)p.z;
    }
    __shared__ double red[256][3];
    red[t][0] = L; red[t][1] = C; red[t][2] = S;
    __syncthreads();
    for (int s = 128; s > 0; s >>= 1) {
        if (t < s) {
            red[t][0] += red[t + s][0];
            red[t][1] += red[t + s][1];
            red[t][2] += red[t + s][2];
        }
        __syncthreads();
    }
    if (t < 3) out[t] = (float)(red[0][t] * INV_NPIX);
}

extern "C" void kernel_launch(void* const* d_in, const int* in_sizes, int n_in,
                              void* d_out, int out_size, void* d_ws, size_t ws_size,
                              hipStream_t stream) {
    const float* img1 = (const float*)d_in[0];
    const float* img2 = (const float*)d_in[1];
    const float* win  = (const float*)d_in[2];
    float* out = (float*)d_out;
    float4* part = (float4*)d_ws;                  // NBLK * 16 B = 15360 B

    ssim_main<<<NBLK, 64 * WPB, 0, stream>>>(img1, img2, win, part);
    ssim_fin<<<1, 256, 0, stream>>>(part, out);
}

// Round 6
// 380.032 us; speedup vs baseline: 1.0549x; 1.0549x over previous
//
#include <hip/hip_runtime.h>
#include <math.h>

#define IMG 512
#define PLANES 96            // 32 N * 3 C
#define XS_W 54              // valid output columns per wave (64 lanes - 10 halo)
#define NXS 10               // ceil(512/54)
#define YS_H 128             // output rows per wave
#define NYS 4                // 512/128
#define WPB 4                // waves per block
#define NBLK ((PLANES * NXS * NYS) / WPB)   // 960 blocks
#define INV_NPIX (1.0 / 25165824.0)

// ws layout: float4 part[NBLK] (15360 B) — per-block partial sums, plain stores.

static __device__ __forceinline__ float rflf(float x) {
    return __int_as_float(__builtin_amdgcn_readfirstlane(__float_as_int(x)));
}

// DPP wave-wide lane shifts (VALU pipe). wave_shr:1 (0x138): lane i reads lane i-1.
// wave_shl:1 (0x130): lane i reads lane i+1. bound_ctrl: OOB lanes read 0 —
// consumed only by halo lanes that never emit.
static __device__ __forceinline__ float dpp_shr1(float x) {
    return __int_as_float(__builtin_amdgcn_mov_dpp(__float_as_int(x), 0x138, 0xF, 0xF, true));
}
static __device__ __forceinline__ float dpp_shl1(float x) {
    return __int_as_float(__builtin_amdgcn_mov_dpp(__float_as_int(x), 0x130, 0xF, 0xF, true));
}

// One row step, phase P = t % 11. Computes on row t (x1a/x2a), PREFETCHES row
// t+2 (2-step-deep pipeline: load issued here is first consumed two steps
// later, giving ~2 steps of arithmetic to cover L3/HBM latency).
// Vertical ring: slot (P+j+1)%11 += g[10-j]*H; j==10 overwrites the slot
// emitted last step (mul, no zeroing). Emit slot (P+1)%11.
// Arithmetic and accumulation order identical to the verified R4 kernel.
template<int P, bool EMIT>
__device__ __forceinline__ void row_step(
    int T, int y0, bool col_ok,
    const float* __restrict__ p1, const float* __restrict__ p2,
    float& x1a, float& x2a, float& x1b, float& x2b, const float (&g)[11],
    float (&A)[5][11], bool out_ok, float& sL, float& sC, float& sS)
{
    const int t = T + P;
    // ---- prefetch row t+2 (coalesced: lane = column) ----
    const int gy2 = y0 - 3 + t;
    float nx1 = 0.f, nx2 = 0.f;
    if (col_ok && (unsigned)gy2 < IMG) {
        int off = gy2 * IMG;
        nx1 = p1[off];
        nx2 = p2[off];
    }
    // ---- horizontal window on row t: left chain materialized, right rolled ----
    const float x1 = x1a, x2 = x2a;
    float a4 = dpp_shr1(x1), b4 = dpp_shr1(x2);
    float a3 = dpp_shr1(a4), b3 = dpp_shr1(b4);
    float a2 = dpp_shr1(a3), b2r = dpp_shr1(b3);
    float a1 = dpp_shr1(a2), b1r = dpp_shr1(b2r);
    float a0 = dpp_shr1(a1), b0 = dpp_shr1(b1r);
    // j = 0
    float t1 = g[0] * a0, t2 = g[0] * b0;
    float H1 = t1, H2 = t2;
    float H11 = t1 * a0, H22 = t2 * b0, H12 = t1 * b0;
#define HACC(J, AJ, BJ)                                   \
    t1 = g[J] * (AJ); t2 = g[J] * (BJ);                   \
    H1 += t1; H2 += t2;                                   \
    H11 = fmaf(t1, (AJ), H11);                            \
    H22 = fmaf(t2, (BJ), H22);                            \
    H12 = fmaf(t1, (BJ), H12);
    HACC(1, a1, b1r)
    HACC(2, a2, b2r)
    HACC(3, a3, b3)
    HACC(4, a4, b4)
    HACC(5, x1, x2)
    float ar = dpp_shl1(x1), br = dpp_shl1(x2);
    HACC(6, ar, br)
    ar = dpp_shl1(ar); br = dpp_shl1(br);
    HACC(7, ar, br)
    ar = dpp_shl1(ar); br = dpp_shl1(br);
    HACC(8, ar, br)
    ar = dpp_shl1(ar); br = dpp_shl1(br);
    HACC(9, ar, br)
    ar = dpp_shl1(ar); br = dpp_shl1(br);
    HACC(10, ar, br)
#undef HACC
    // ---- vertical ring accumulate (static slot indices, t ≡ P mod 11) ----
    #pragma unroll
    for (int j = 0; j < 11; ++j) {
        const int s = (P + j + 1) % 11;
        float w = g[10 - j];
        if (j == 10) {                             // fresh slot (== P): overwrite
            A[0][s] = w * H1;
            A[1][s] = w * H2;
            A[2][s] = w * H11;
            A[3][s] = w * H22;
            A[4][s] = w * H12;
        } else {
            A[0][s] = fmaf(w, H1,  A[0][s]);
            A[1][s] = fmaf(w, H2,  A[1][s]);
            A[2][s] = fmaf(w, H11, A[2][s]);
            A[3][s] = fmaf(w, H22, A[3][s]);
            A[4][s] = fmaf(w, H12, A[4][s]);
        }
    }
    // ---- emit output row r = t-10 (slot (P+1)%11) ----
    if (EMIT) {
        const int es = (P + 1) % 11;
        float mu1 = A[0][es], mu2 = A[1][es];
        float x11 = A[2][es], x22 = A[3][es], x12 = A[4][es];
        float mu1s = mu1 * mu1, mu2s = mu2 * mu2, mu12 = mu1 * mu2;
        float v1 = x11 - mu1s, v2 = x22 - mu2s, v12 = x12 - mu12;
        float q1 = fabsf(v1), q2 = fabsf(v2);
        float q12 = sqrtf(q1 * q2);                // sqrt(a1)*sqrt(a2)
        const float C1 = 1e-4f, C2 = 9e-4f, C3 = 4.5e-4f;
        float eL = __fdividef(2.f * mu12 + C1, mu1s + mu2s + C1);
        float eC = __fdividef(2.f * q12 + C2, q1 + q2 + C2);
        float eS = __fdividef(v12 + C3, q12 + C3);
        if (out_ok) { sL += eL; sC += eC; sS += eS; }
    }
    // ---- rotate the 2-deep pipeline (pure renaming in the unrolled body) ----
    x1a = x1b; x2a = x2b;
    x1b = nx1; x2b = nx2;
}

__global__ __launch_bounds__(256, 4) void ssim_main(
    const float* __restrict__ img1, const float* __restrict__ img2,
    const float* __restrict__ win, float4* __restrict__ part)
{
    const int lane = threadIdx.x & 63;
    const int widx = threadIdx.x >> 6;
    const int wid  = blockIdx.x * WPB + widx;
    const int plane = wid / (NXS * NYS);
    const int rem   = wid % (NXS * NYS);
    const int ys = rem / NXS, xs = rem % NXS;
    const int x0 = xs * XS_W;
    const int y0 = ys * YS_H;
    const int col = x0 - 5 + lane;                 // this lane's image column
    const bool col_ok = (unsigned)col < IMG;
    const bool out_ok = (lane >= 5) && (lane <= 58) && col_ok;

    // separable 1-D Gaussian from diagonal of 2-D window (channel 0):
    // w2d[i][i] = g[i]^2 -> g[i] = sqrt(win[i*12]). Uniform -> SGPRs.
    float g[11];
    #pragma unroll
    for (int j = 0; j < 11; ++j) g[j] = rflf(sqrtf(win[j * 12]));

    const float* p1 = img1 + (size_t)plane * (IMG * IMG) + col;
    const float* p2 = img2 + (size_t)plane * (IMG * IMG) + col;

    // warm the pipeline: row t=0 (gy=y0-5) -> xa, row t=1 (gy=y0-4) -> xb
    float x1a = 0.f, x2a = 0.f, x1b = 0.f, x2b = 0.f;
    {
        int gy = y0 - 5;
        if (col_ok && (unsigned)gy < IMG) { x1a = p1[gy * IMG]; x2a = p2[gy * IMG]; }
        gy = y0 - 4;
        if (col_ok && (unsigned)gy < IMG) { x1b = p1[gy * IMG]; x2b = p2[gy * IMG]; }
    }

    float A[5][11];
    #pragma unroll
    for (int q = 0; q < 5; ++q)
        #pragma unroll
        for (int s = 0; s < 11; ++s) A[q][s] = 0.f;

    float sL = 0.f, sC = 0.f, sS = 0.f;

    // t = 0..10: ring warm-up (no emit until t=10)
    row_step<0,false>(0, y0, col_ok, p1, p2, x1a, x2a, x1b, x2b, g, A, out_ok, sL, sC, sS);
    row_step<1,false>(0, y0, col_ok, p1, p2, x1a, x2a, x1b, x2b, g, A, out_ok, sL, sC, sS);
    row_step<2,false>(0, y0, col_ok, p1, p2, x1a, x2a, x1b, x2b, g, A, out_ok, sL, sC, sS);
    row_step<3,false>(0, y0, col_ok, p1, p2, x1a, x2a, x1b, x2b, g, A, out_ok, sL, sC, sS);
    row_step<4,false>(0, y0, col_ok, p1, p2, x1a, x2a, x1b, x2b, g, A, out_ok, sL, sC, sS);
    row_step<5,false>(0, y0, col_ok, p1, p2, x1a, x2a, x1b, x2b, g, A, out_ok, sL, sC, sS);
    row_step<6,false>(0, y0, col_ok, p1, p2, x1a, x2a, x1b, x2b, g, A, out_ok, sL, sC, sS);
    row_step<7,false>(0, y0, col_ok, p1, p2, x1a, x2a, x1b, x2b, g, A, out_ok, sL, sC, sS);
    row_step<8,false>(0, y0, col_ok, p1, p2, x1a, x2a, x1b, x2b, g, A, out_ok, sL, sC, sS);
    row_step<9,false>(0, y0, col_ok, p1, p2, x1a, x2a, x1b, x2b, g, A, out_ok, sL, sC, sS);
    row_step<10,true>(0, y0, col_ok, p1, p2, x1a, x2a, x1b, x2b, g, A, out_ok, sL, sC, sS);

    #pragma unroll 1
    for (int T = 11; T < 132; T += 11) {           // t = 11..131, all emit
        row_step<0,true>(T, y0, col_ok, p1, p2, x1a, x2a, x1b, x2b, g, A, out_ok, sL, sC, sS);
        row_step<1,true>(T, y0, col_ok, p1, p2, x1a, x2a, x1b, x2b, g, A, out_ok, sL, sC, sS);
        row_step<2,true>(T, y0, col_ok, p1, p2, x1a, x2a, x1b, x2b, g, A, out_ok, sL, sC, sS);
        row_step<3,true>(T, y0, col_ok, p1, p2, x1a, x2a, x1b, x2b, g, A, out_ok, sL, sC, sS);
        row_step<4,true>(T, y0, col_ok, p1, p2, x1a, x2a, x1b, x2b, g, A, out_ok, sL, sC, sS);
        row_step<5,true>(T, y0, col_ok, p1, p2, x1a, x2a, x1b, x2b, g, A, out_ok, sL, sC, sS);
        row_step<6,true>(T, y0, col_ok, p1, p2, x1a, x2a, x1b, x2b, g, A, out_ok, sL, sC, sS);
        row_step<7,true>(T, y0, col_ok, p1, p2, x1a, x2a, x1b, x2b, g, A, out_ok, sL, sC, sS);
        row_step<8,true>(T, y0, col_ok, p1, p2, x1a, x2a, x1b, x2b, g, A, out_ok, sL, sC, sS);
        row_step<9,true>(T, y0, col_ok, p1, p2, x1a, x2a, x1b, x2b, g, A, out_ok, sL, sC, sS);
        row_step<10,true>(T, y0, col_ok, p1, p2, x1a, x2a, x1b, x2b, g, A, out_ok, sL, sC, sS);
    }
    // tail: t = 132..137
    row_step<0,true>(132, y0, col_ok, p1, p2, x1a, x2a, x1b, x2b, g, A, out_ok, sL, sC, sS);
    row_step<1,true>(132, y0, col_ok, p1, p2, x1a, x2a, x1b, x2b, g, A, out_ok, sL, sC, sS);
    row_step<2,true>(132, y0, col_ok, p1, p2, x1a, x2a, x1b, x2b, g, A, out_ok, sL, sC, sS);
    row_step<3,true>(132, y0, col_ok, p1, p2, x1a, x2a, x1b, x2b, g, A, out_ok, sL, sC, sS);
    row_step<4,true>(132, y0, col_ok, p1, p2, x1a, x2a, x1b, x2b, g, A, out_ok, sL, sC, sS);
    row_step<5,true>(132, y0, col_ok, p1, p2, x1a, x2a, x1b, x2b, g, A, out_ok, sL, sC, sS);

    // ---- wave reduction, then block reduction via tiny LDS, one plain store ----
    #pragma unroll
    for (int off = 32; off > 0; off >>= 1) {
        sL += __shfl_down(sL, off, 64);
        sC += __shfl_down(sC, off, 64);
        sS += __shfl_down(sS, off, 64);
    }
    __shared__ float red[WPB][4];
    if (lane == 0) { red[widx][0] = sL; red[widx][1] = sC; red[widx][2] = sS; }
    __syncthreads();
    if (threadIdx.x == 0) {
        float L = 0.f, C = 0.f, S = 0.f;
        #pragma unroll
        for (int w = 0; w < WPB; ++w) { L += red[w][0]; C += red[w][1]; S += red[w][2]; }
        part[blockIdx.x] = make_float4(L, C, S, 0.f);
    }
}

__global__ void ssim_fin(const float4* __restrict__ part, float* __restrict__ out) {
    const int t = threadIdx.x;
    double L = 0.0, C = 0.0, S = 0.0;
    for (int i = t; i < NBLK; i += 256) {
        float4 p = part[i];
        L += (double)p.x; C += (double)p.y; S += (double)p.z;
    }
    __shared__ double red[256][3];
    red[t][0] = L; red[t][1] = C; red[t][2] = S;
    __syncthreads();
    for (int s = 128; s > 0; s >>= 1) {
        if (t < s) {
            red[t][0] += red[t + s][0];
            red[t][1] += red[t + s][1];
            red[t][2] += red[t + s][2];
        }
        __syncthreads();
    }
    if (t < 3) out[t] = (float)(red[0][t] * INV_NPIX);
}

extern "C" void kernel_launch(void* const* d_in, const int* in_sizes, int n_in,
                              void* d_out, int out_size, void* d_ws, size_t ws_size,
                              hipStream_t stream) {
    const float* img1 = (const float*)d_in[0];
    const float* img2 = (const float*)d_in[1];
    const float* win  = (const float*)d_in[2];
    float* out = (float*)d_out;
    float4* part = (float4*)d_ws;                  // NBLK * 16 B = 15360 B

    ssim_main<<<NBLK, 64 * WPB, 0, stream>>>(img1, img2, win, part);
    ssim_fin<<<1, 256, 0, stream>>>(part, out);
}